// Round 10
// baseline (179.406 us; speedup 1.0000x reference)
//
#include <hip/hip_runtime.h>
#include <hip/hip_bf16.h>
#include <math.h>

// SemiCRF dense span scores, MI355X gfx950.  Round 8 structure:
// 1024 blocks x 512 threads (8 waves), one i per wave -> 32 waves/CU cap.
// LDS holds ONLY c1/c2 prefix tables (24.6 KB) + len LUT; x scanned straight
// from global by wave0 lanes<28. Per-tile agg fragments built in registers
// (custom k-map == W1 fragment k-map, so HW k-pairing cancels); b1 folded in
// as a constant-1.0 input column; branch-free main loop via uniform quad-B +
// cndmask overwrite for q==3; 3-parallel-shuffle q-reduction.

typedef __attribute__((ext_vector_type(4))) float f32x4;
typedef __attribute__((ext_vector_type(8))) short bf16x8;
typedef __attribute__((ext_vector_type(4))) unsigned int u32x4;

#define L_SEQ 8192
#define F_DIM 26
#define SEG 100
#define HID 64
#define BI 8
#define REG_ROWS (BI + SEG - 1)            /* 107 x-rows per block */
#define C_STRIDE 28                        /* f32 per c-row (16B-multiple) */
#define C_BYTES ((REG_ROWS + 1) * C_STRIDE * 4)   /* 12096 */
#define LUT_OFF (2 * C_BYTES)              /* 24192 */
#define LUT_N 112                          /* len/loglen, covers junk l<=112 */
#define SMEM_BYTES (LUT_OFF + LUT_N * 4)   /* 24640 -> LDS allows 6 blk/CU */

__device__ __forceinline__ unsigned short f2bf(float v) {   // setup-only path
    unsigned u = __builtin_bit_cast(unsigned, v);
    u += 0x7FFFu + ((u >> 16) & 1u);   // round-to-nearest-even
    return (unsigned short)(u >> 16);
}
__device__ __forceinline__ unsigned pk(unsigned short a, unsigned short b) {
    return (unsigned)a | ((unsigned)b << 16);
}
__device__ __forceinline__ unsigned cvtpk(float lo, float hi) {  // hot path
    unsigned r;
    asm("v_cvt_pk_bf16_f32 %0, %1, %2" : "=v"(r) : "v"(lo), "v"(hi));
    return r;
}

__global__ __launch_bounds__(512, 8)
void semicrf_kernel(const float* __restrict__ x, const float* __restrict__ W1,
                    const float* __restrict__ b1, const float* __restrict__ W2,
                    const float* __restrict__ b2, float* __restrict__ out) {
    __shared__ __align__(16) char smem[SMEM_BYTES];
    float*    c1    = (float*)smem;
    float*    c2    = (float*)(smem + C_BYTES);
    unsigned* lenlt = (unsigned*)(smem + LUT_OFF);

    const int tid  = threadIdx.x;
    const int lane = tid & 63;
    const int wave = tid >> 6;              // 0..7 == bi (one i per wave)
    const int i0   = blockIdx.x * BI;

    // ---- wave0 lanes<28: serial prefix scan straight from global (L2-hot) --
    if (tid < C_STRIDE) {
        const int f = tid;
        const bool live = (f < F_DIM);
        const float* xp = x + i0 * F_DIM + f;
        const int rmax = min(REG_ROWS, L_SEQ - i0);
        float s1 = 0.f, s2 = 0.f;
        c1[f] = 0.f;
        c2[f] = 0.f;
        int rr = 0;
#pragma unroll 8
        for (; rr < rmax; ++rr) {
            float xv = live ? xp[rr * F_DIM] : 0.f;
            s1 += xv;
            s2 = fmaf(xv, xv, s2);
            c1[(rr + 1) * C_STRIDE + f] = s1;
            c2[(rr + 1) * C_STRIDE + f] = s2;
        }
        for (; rr < REG_ROWS; ++rr) {       // rows past end of sequence
            c1[(rr + 1) * C_STRIDE + f] = s1;
            c2[(rr + 1) * C_STRIDE + f] = s2;
        }
    }
    // ---- wave2: len/loglen LUT ----
    if (tid >= 128 && tid < 128 + LUT_N) {
        const int t = tid - 128;
        float lf = (float)(t + 1);
        lenlt[t] = pk(f2bf(lf * 0.002f), f2bf(logf(lf + 1e-6f) * (1.0f / 6.0f)));
    }

    // ---- every wave: W1^T fragments (custom k-map, b1 folded) + W2 quads ---
    // k-map (q=lane>>4, elem j), s=0 -> A0, s=1 -> A1:
    //  q<3 : j<4 -> f=4q+j ; j>=4 -> f=16+4q+(j-4)  (f>=26 -> zero weight)
    //        s=0: mean (wr=f), s=1: var (wr=26+f)
    //  q=3 : j<4 -> f=12+j ; s=0: j=4 -> len(52), j=5 -> loglen(53),
    //        j=6 -> b1 column (B supplies constant 1.0); all else zero.
    const int r = lane & 15;   // A row (hid low) / B col (seg_row) / D col
    const int q = lane >> 4;
    bf16x8 wfrag[2][4];
#pragma unroll
    for (int s = 0; s < 2; ++s) {
#pragma unroll
        for (int t = 0; t < 4; ++t) {
            bf16x8 v;
#pragma unroll
            for (int j = 0; j < 8; ++j) {
                float wv = 0.f;
                if (q < 3 || j < 4) {
                    int f = (j < 4) ? (4 * q + j) : (16 + 4 * q + (j - 4));
                    if (f < 26) wv = W1[((s == 0) ? f : 26 + f) * HID + (t * 16 + r)];
                } else if (s == 0 && j == 4) wv = W1[52 * HID + (t * 16 + r)];
                else if (s == 0 && j == 5)   wv = W1[53 * HID + (t * 16 + r)];
                else if (s == 0 && j == 6)   wv = b1[t * 16 + r];
                v[j] = (short)f2bf(wv);
            }
            wfrag[s][t] = v;
        }
    }
    // D[row=hid t*16+q*4+g][col=seg_row r] -> this lane needs W2 at q*4+g
    f32x4 w2v[4];
#pragma unroll
    for (int t = 0; t < 4; ++t)
        w2v[t] = *(const f32x4*)(W2 + t * 16 + q * 4);
    const float b2v = b2[0];

    __syncthreads();

    // ---- main: one i per wave, 7 l-chunks, fragments in registers ----
    const bool q3 = (q == 3);
    const int f0A = 4 * q;
    const int f0B = q3 ? 12 : 16 + 4 * q;   // q3: harmless cols, overwritten
    const int bi = wave;
    const int i = i0 + bi;
    const float* c1b = c1 + bi * C_STRIDE;
    const float* c2b = c2 + bi * C_STRIDE;
    const f32x4 c1iA = *(const f32x4*)(c1b + f0A);
    const f32x4 c2iA = *(const f32x4*)(c2b + f0A);
    const f32x4 c1iB = *(const f32x4*)(c1b + f0B);
    const f32x4 c2iB = *(const f32x4*)(c2b + f0B);

    for (int lc = 0; lc < 7; ++lc) {
        const int lm1 = lc * 16 + r;                 // l-1 for this lane
        const float inv_l = __builtin_amdgcn_rcpf((float)(lm1 + 1));
        const int cj = min(bi + lm1 + 1, REG_ROWS);  // clamp junk (l>100)
        const float* c1j = c1 + cj * C_STRIDE;
        const float* c2j = c2 + cj * C_STRIDE;

        union { u32x4 u; bf16x8 h; } A0, A1;
        {   // quad A: f = f0A..f0A+3 (all lanes)
            f32x4 m = (*(const f32x4*)(c1j + f0A) - c1iA) * inv_l;
            f32x4 t = (*(const f32x4*)(c2j + f0A) - c2iA) * inv_l;
            f32x4 v = t - m * m;
            A0.u.x = cvtpk(m[0], m[1]);
            A0.u.y = cvtpk(m[2], m[3]);
            A1.u.x = cvtpk(v[0], v[1]);
            A1.u.y = cvtpk(v[2], v[3]);
        }
        {   // quad B: uniform for all lanes; q3 lanes overwritten below
            f32x4 m = (*(const f32x4*)(c1j + f0B) - c1iB) * inv_l;
            f32x4 t = (*(const f32x4*)(c2j + f0B) - c2iB) * inv_l;
            f32x4 v = t - m * m;
            const unsigned lv = lenlt[lm1];
            A0.u.z = q3 ? lv          : cvtpk(m[0], m[1]);
            A0.u.w = q3 ? 0x00003F80u : cvtpk(m[2], m[3]);  // bf16(1.0) = b1 col
            A1.u.z = q3 ? 0u          : cvtpk(v[0], v[1]);
            A1.u.w = q3 ? 0u          : cvtpk(v[2], v[3]);
        }

        f32x4 acc0 = {0.f, 0.f, 0.f, 0.f};
        f32x4 acc1 = {0.f, 0.f, 0.f, 0.f};
        f32x4 acc2 = {0.f, 0.f, 0.f, 0.f};
        f32x4 acc3 = {0.f, 0.f, 0.f, 0.f};
        acc0 = __builtin_amdgcn_mfma_f32_16x16x32_bf16(wfrag[0][0], A0.h, acc0, 0, 0, 0);
        acc1 = __builtin_amdgcn_mfma_f32_16x16x32_bf16(wfrag[0][1], A0.h, acc1, 0, 0, 0);
        acc2 = __builtin_amdgcn_mfma_f32_16x16x32_bf16(wfrag[0][2], A0.h, acc2, 0, 0, 0);
        acc3 = __builtin_amdgcn_mfma_f32_16x16x32_bf16(wfrag[0][3], A0.h, acc3, 0, 0, 0);
        acc0 = __builtin_amdgcn_mfma_f32_16x16x32_bf16(wfrag[1][0], A1.h, acc0, 0, 0, 0);
        acc1 = __builtin_amdgcn_mfma_f32_16x16x32_bf16(wfrag[1][1], A1.h, acc1, 0, 0, 0);
        acc2 = __builtin_amdgcn_mfma_f32_16x16x32_bf16(wfrag[1][2], A1.h, acc2, 0, 0, 0);
        acc3 = __builtin_amdgcn_mfma_f32_16x16x32_bf16(wfrag[1][3], A1.h, acc3, 0, 0, 0);

        // epilogue: p = sum_t sum_g relu(h) * w2 (b1 inside h via 1.0 column)
        float p0 = 0.f, p1 = 0.f, p2 = 0.f, p3 = 0.f;
#define EPI(ACC, PT, T)                                             \
        PT = fmaf(fmaxf(ACC[0], 0.f), w2v[T][0], PT);               \
        PT = fmaf(fmaxf(ACC[1], 0.f), w2v[T][1], PT);               \
        PT = fmaf(fmaxf(ACC[2], 0.f), w2v[T][2], PT);               \
        PT = fmaf(fmaxf(ACC[3], 0.f), w2v[T][3], PT);
        EPI(acc0, p0, 0) EPI(acc1, p1, 1) EPI(acc2, p2, 2) EPI(acc3, p3, 3)
#undef EPI
        const float pA = (p0 + p1) + (p2 + p3);
        const float t16 = __shfl_xor(pA, 16);   // 3 independent bpermutes
        const float t32 = __shfl_xor(pA, 32);
        const float t48 = __shfl_xor(pA, 48);
        const float p = (pA + t16) + (t32 + t48);

        if (lane < 16 && lm1 < SEG)
            out[i * SEG + lm1] = (i + lm1 + 1 <= L_SEQ) ? p + b2v : 0.0f;
    }
}

extern "C" void kernel_launch(void* const* d_in, const int* in_sizes, int n_in,
                              void* d_out, int out_size, void* d_ws, size_t ws_size,
                              hipStream_t stream) {
    const float* x  = (const float*)d_in[0];
    const float* W1 = (const float*)d_in[1];
    const float* b1 = (const float*)d_in[2];
    const float* W2 = (const float*)d_in[3];
    const float* b2 = (const float*)d_in[4];
    float* out = (float*)d_out;
    semicrf_kernel<<<dim3(L_SEQ / BI), dim3(512), 0, stream>>>(x, W1, b1, W2, b2, out);
}

// Round 11
// 103.350 us; speedup vs baseline: 1.7359x; 1.7359x over previous
//
#include <hip/hip_runtime.h>
#include <hip/hip_bf16.h>
#include <math.h>

// SemiCRF dense span scores, MI355X gfx950.  Round 11 structure:
// 1024 blocks x 256 threads (4 waves, 2 i's per wave), __launch_bounds__(256,5)
// -> ~102-reg budget (no spill; round-10's (512,8) forced 32 arch VGPRs and
// spilled: FETCH 249MB). LDS holds ONLY c1/c2 (24.6 KB) + len LUT -> 6 blk/CU
// by LDS, 5 by regs -> 20 waves/CU cap (vs 16 in round 7). x scanned straight
// from global (L2-resident) by wave0 lanes<28. Agg fragments in registers
// (k-map == W1 fragment k-map -> HW k-pairing cancels); b1 folded as 1.0
// input column; uniform quad-B + cndmask for q==3; 3-parallel-shuffle reduce.

typedef __attribute__((ext_vector_type(4))) float f32x4;
typedef __attribute__((ext_vector_type(8))) short bf16x8;
typedef __attribute__((ext_vector_type(4))) unsigned int u32x4;

#define L_SEQ 8192
#define F_DIM 26
#define SEG 100
#define HID 64
#define BI 8
#define REG_ROWS (BI + SEG - 1)            /* 107 x-rows per block */
#define C_STRIDE 28                        /* f32 per c-row (16B-multiple) */
#define C_BYTES ((REG_ROWS + 1) * C_STRIDE * 4)   /* 12096 */
#define LUT_OFF (2 * C_BYTES)              /* 24192 */
#define LUT_N 112                          /* len/loglen, covers junk l<=112 */
#define SMEM_BYTES (LUT_OFF + LUT_N * 4)   /* 24640 B */

__device__ __forceinline__ unsigned short f2bf(float v) {   // setup-only path
    unsigned u = __builtin_bit_cast(unsigned, v);
    u += 0x7FFFu + ((u >> 16) & 1u);   // round-to-nearest-even
    return (unsigned short)(u >> 16);
}
__device__ __forceinline__ unsigned pk(unsigned short a, unsigned short b) {
    return (unsigned)a | ((unsigned)b << 16);
}
__device__ __forceinline__ unsigned cvtpk(float lo, float hi) {  // hot path
    unsigned r;
    asm("v_cvt_pk_bf16_f32 %0, %1, %2" : "=v"(r) : "v"(lo), "v"(hi));
    return r;
}

__global__ __launch_bounds__(256, 5)
void semicrf_kernel(const float* __restrict__ x, const float* __restrict__ W1,
                    const float* __restrict__ b1, const float* __restrict__ W2,
                    const float* __restrict__ b2, float* __restrict__ out) {
    __shared__ __align__(16) char smem[SMEM_BYTES];
    float*    c1    = (float*)smem;
    float*    c2    = (float*)(smem + C_BYTES);
    unsigned* lenlt = (unsigned*)(smem + LUT_OFF);

    const int tid  = threadIdx.x;
    const int lane = tid & 63;
    const int wave = tid >> 6;              // 0..3
    const int i0   = blockIdx.x * BI;

    // ---- wave0 lanes<28: serial prefix scan straight from global (L2-hot) --
    if (tid < C_STRIDE) {
        const int f = tid;
        const bool live = (f < F_DIM);
        const float* xp = x + i0 * F_DIM + f;
        const int rmax = min(REG_ROWS, L_SEQ - i0);
        float s1 = 0.f, s2 = 0.f;
        c1[f] = 0.f;
        c2[f] = 0.f;
        int rr = 0;
#pragma unroll 8
        for (; rr < rmax; ++rr) {
            float xv = live ? xp[rr * F_DIM] : 0.f;
            s1 += xv;
            s2 = fmaf(xv, xv, s2);
            c1[(rr + 1) * C_STRIDE + f] = s1;
            c2[(rr + 1) * C_STRIDE + f] = s2;
        }
        for (; rr < REG_ROWS; ++rr) {       // rows past end of sequence
            c1[(rr + 1) * C_STRIDE + f] = s1;
            c2[(rr + 1) * C_STRIDE + f] = s2;
        }
    }
    // ---- waves 2-3: len/loglen LUT ----
    if (tid >= 128 && tid < 128 + LUT_N) {
        const int t = tid - 128;
        float lf = (float)(t + 1);
        lenlt[t] = pk(f2bf(lf * 0.002f), f2bf(logf(lf + 1e-6f) * (1.0f / 6.0f)));
    }

    // ---- every wave: W1^T fragments (custom k-map, b1 folded) + W2 quads ---
    // k-map (q=lane>>4, elem j), s=0 -> A0, s=1 -> A1:
    //  q<3 : j<4 -> f=4q+j ; j>=4 -> f=16+4q+(j-4)  (f>=26 -> zero weight)
    //        s=0: mean (wr=f), s=1: var (wr=26+f)
    //  q=3 : j<4 -> f=12+j ; s=0: j=4 -> len(52), j=5 -> loglen(53),
    //        j=6 -> b1 column (B supplies constant 1.0); all else zero.
    const int r = lane & 15;   // A row (hid low) / B col (seg_row) / D col
    const int q = lane >> 4;
    bf16x8 wfrag[2][4];
#pragma unroll
    for (int s = 0; s < 2; ++s) {
#pragma unroll
        for (int t = 0; t < 4; ++t) {
            bf16x8 v;
#pragma unroll
            for (int j = 0; j < 8; ++j) {
                float wv = 0.f;
                if (q < 3 || j < 4) {
                    int f = (j < 4) ? (4 * q + j) : (16 + 4 * q + (j - 4));
                    if (f < 26) wv = W1[((s == 0) ? f : 26 + f) * HID + (t * 16 + r)];
                } else if (s == 0 && j == 4) wv = W1[52 * HID + (t * 16 + r)];
                else if (s == 0 && j == 5)   wv = W1[53 * HID + (t * 16 + r)];
                else if (s == 0 && j == 6)   wv = b1[t * 16 + r];
                v[j] = (short)f2bf(wv);
            }
            wfrag[s][t] = v;
        }
    }
    // D[row=hid t*16+q*4+g][col=seg_row r] -> this lane needs W2 at q*4+g
    f32x4 w2v[4];
#pragma unroll
    for (int t = 0; t < 4; ++t)
        w2v[t] = *(const f32x4*)(W2 + t * 16 + q * 4);
    const float b2v = b2[0];

    __syncthreads();

    // ---- main: 2 i's per wave, 7 l-chunks each, fragments in registers ----
    const bool q3 = (q == 3);
    const int f0A = 4 * q;
    const int f0B = q3 ? 12 : 16 + 4 * q;   // q3: harmless cols, overwritten

    for (int bih = 0; bih < 2; ++bih) {
        const int bi = wave + 4 * bih;
        const int i = i0 + bi;
        const float* c1b = c1 + bi * C_STRIDE;
        const float* c2b = c2 + bi * C_STRIDE;
        const f32x4 c1iA = *(const f32x4*)(c1b + f0A);
        const f32x4 c2iA = *(const f32x4*)(c2b + f0A);
        const f32x4 c1iB = *(const f32x4*)(c1b + f0B);
        const f32x4 c2iB = *(const f32x4*)(c2b + f0B);

        for (int lc = 0; lc < 7; ++lc) {
            const int lm1 = lc * 16 + r;                 // l-1 for this lane
            const float inv_l = __builtin_amdgcn_rcpf((float)(lm1 + 1));
            const int cj = min(bi + lm1 + 1, REG_ROWS);  // clamp junk (l>100)
            const float* c1j = c1 + cj * C_STRIDE;
            const float* c2j = c2 + cj * C_STRIDE;

            union { u32x4 u; bf16x8 h; } A0, A1;
            {   // quad A: f = f0A..f0A+3 (all lanes)
                f32x4 m = (*(const f32x4*)(c1j + f0A) - c1iA) * inv_l;
                f32x4 t = (*(const f32x4*)(c2j + f0A) - c2iA) * inv_l;
                f32x4 v = t - m * m;
                A0.u.x = cvtpk(m[0], m[1]);
                A0.u.y = cvtpk(m[2], m[3]);
                A1.u.x = cvtpk(v[0], v[1]);
                A1.u.y = cvtpk(v[2], v[3]);
            }
            {   // quad B: uniform for all lanes; q3 lanes overwritten below
                f32x4 m = (*(const f32x4*)(c1j + f0B) - c1iB) * inv_l;
                f32x4 t = (*(const f32x4*)(c2j + f0B) - c2iB) * inv_l;
                f32x4 v = t - m * m;
                const unsigned lv = lenlt[lm1];
                A0.u.z = q3 ? lv          : cvtpk(m[0], m[1]);
                A0.u.w = q3 ? 0x00003F80u : cvtpk(m[2], m[3]);  // bf16(1.0)=b1 col
                A1.u.z = q3 ? 0u          : cvtpk(v[0], v[1]);
                A1.u.w = q3 ? 0u          : cvtpk(v[2], v[3]);
            }

            f32x4 acc0 = {0.f, 0.f, 0.f, 0.f};
            f32x4 acc1 = {0.f, 0.f, 0.f, 0.f};
            f32x4 acc2 = {0.f, 0.f, 0.f, 0.f};
            f32x4 acc3 = {0.f, 0.f, 0.f, 0.f};
            acc0 = __builtin_amdgcn_mfma_f32_16x16x32_bf16(wfrag[0][0], A0.h, acc0, 0, 0, 0);
            acc1 = __builtin_amdgcn_mfma_f32_16x16x32_bf16(wfrag[0][1], A0.h, acc1, 0, 0, 0);
            acc2 = __builtin_amdgcn_mfma_f32_16x16x32_bf16(wfrag[0][2], A0.h, acc2, 0, 0, 0);
            acc3 = __builtin_amdgcn_mfma_f32_16x16x32_bf16(wfrag[0][3], A0.h, acc3, 0, 0, 0);
            acc0 = __builtin_amdgcn_mfma_f32_16x16x32_bf16(wfrag[1][0], A1.h, acc0, 0, 0, 0);
            acc1 = __builtin_amdgcn_mfma_f32_16x16x32_bf16(wfrag[1][1], A1.h, acc1, 0, 0, 0);
            acc2 = __builtin_amdgcn_mfma_f32_16x16x32_bf16(wfrag[1][2], A1.h, acc2, 0, 0, 0);
            acc3 = __builtin_amdgcn_mfma_f32_16x16x32_bf16(wfrag[1][3], A1.h, acc3, 0, 0, 0);

            // epilogue: p = sum_t sum_g relu(h) * w2 (b1 inside h via 1.0 col)
            float p0 = 0.f, p1 = 0.f, p2 = 0.f, p3 = 0.f;
#define EPI(ACC, PT, T)                                             \
            PT = fmaf(fmaxf(ACC[0], 0.f), w2v[T][0], PT);           \
            PT = fmaf(fmaxf(ACC[1], 0.f), w2v[T][1], PT);           \
            PT = fmaf(fmaxf(ACC[2], 0.f), w2v[T][2], PT);           \
            PT = fmaf(fmaxf(ACC[3], 0.f), w2v[T][3], PT);
            EPI(acc0, p0, 0) EPI(acc1, p1, 1) EPI(acc2, p2, 2) EPI(acc3, p3, 3)
#undef EPI
            const float pA = (p0 + p1) + (p2 + p3);
            const float t16 = __shfl_xor(pA, 16);   // 3 independent bpermutes
            const float t32 = __shfl_xor(pA, 32);
            const float t48 = __shfl_xor(pA, 48);
            const float p = (pA + t16) + (t32 + t48);

            if (lane < 16 && lm1 < SEG)
                out[i * SEG + lm1] = (i + lm1 + 1 <= L_SEQ) ? p + b2v : 0.0f;
        }
    }
}

extern "C" void kernel_launch(void* const* d_in, const int* in_sizes, int n_in,
                              void* d_out, int out_size, void* d_ws, size_t ws_size,
                              hipStream_t stream) {
    const float* x  = (const float*)d_in[0];
    const float* W1 = (const float*)d_in[1];
    const float* b1 = (const float*)d_in[2];
    const float* W2 = (const float*)d_in[3];
    const float* b2 = (const float*)d_in[4];
    float* out = (float*)d_out;
    semicrf_kernel<<<dim3(L_SEQ / BI), dim3(256), 0, stream>>>(x, W1, b1, W2, b2, out);
}